// Round 4
// baseline (466.321 us; speedup 1.0000x reference)
//
#include <hip/hip_runtime.h>

typedef short s16x8 __attribute__((ext_vector_type(8)));
typedef unsigned short u16x8 __attribute__((ext_vector_type(8)));
typedef float f32x16 __attribute__((ext_vector_type(16)));

__device__ __forceinline__ unsigned short f2bf(float f) {
  unsigned u = __float_as_uint(f);
  u += 0x7fffu + ((u >> 16) & 1u);            // round-to-nearest-even
  return (unsigned short)(u >> 16);
}

__device__ __forceinline__ float tanh_fast(float x) {
  float xc = fminf(15.f, fmaxf(-15.f, x));
  float t = __builtin_amdgcn_exp2f(xc * 2.8853900817779268f); // 2*log2(e)
  return (t - 1.f) * __builtin_amdgcn_rcpf(t + 1.f);
}

// ---- prep: pack W (K,N) fp32 -> bf16 MFMA-B-fragment order, via LDS transpose ----
// chunk c = ((tile*KK + kk)*64 + lane), elems j=0..7:
//   value = W[(kk*16 + (lane>>5)*8 + j) * N + tile*32 + (lane&31)]
// w1p: 16 tiles x 16 kk at ws+0 ; w2p: 16 x 32 at ws+131072 ; w3p: 4 x 32 at ws+393216
__global__ __launch_bounds__(256)
void prep_pack(const float* __restrict__ W1, const float* __restrict__ W2,
               const float* __restrict__ W3, unsigned short* __restrict__ ws) {
  __shared__ unsigned short t[64][65];
  const int b = blockIdx.x;
  const float* W; unsigned short* base; int KK, N, tk, tn;
  if (b < 32)      { W = W1; base = ws;          KK = 16; N = 512; tk = b >> 3;       tn = b & 7; }
  else if (b < 96) { int g = b - 32; W = W2; base = ws + 131072; KK = 32; N = 512; tk = g >> 3; tn = g & 7; }
  else             { int g = b - 96; W = W3; base = ws + 393216; KK = 32; N = 128; tk = g >> 1; tn = g & 1; }

  const int tid = threadIdx.x;
  #pragma unroll
  for (int p = 0; p < 16; ++p) {
    int kl = p * 4 + (tid >> 6);
    int nl = tid & 63;
    t[kl][nl] = f2bf(W[(size_t)(tk * 64 + kl) * N + tn * 64 + nl]);
  }
  __syncthreads();

  const int lane = tid & 63, ln31 = lane & 31, khalf = lane >> 5;
  #pragma unroll
  for (int pass = 0; pass < 2; ++pass) {
    int pair = pass * 4 + (tid >> 6);
    int tn_l = pair & 1, kk_l = pair >> 1;
    int tile = tn * 2 + tn_l, kk = tk * 4 + kk_l;
    u16x8 v;
    #pragma unroll
    for (int j = 0; j < 8; ++j)
      v[j] = t[kk_l * 16 + khalf * 8 + j][tn_l * 32 + ln31];
    *(u16x8*)(base + ((size_t)(tile * KK + kk) * 64 + lane) * 8) = v;
  }
}

// LDS: chunk-major with row rotation; addr(shorts) = ch*512 + ((row+ch)&63)*8 + w
#define LDSIDX(ch, row) (((ch) << 9) + ((((row) + (ch)) & 63) << 3))

// 256 threads = 4 waves; wave tile: 64 rows (mt=2) x 128 cols (nt=4).
// launch_bounds(256,2): 2 waves/EU -> 8 waves/CU -> 256-reg/wave budget
// (acc=128 AGPR + ~100 arch for 1-deep pipeline, no spill).
__global__ __launch_bounds__(256, 2)
void mlp_limit_kernel(const float* __restrict__ x,
                      const float* __restrict__ b1, const float* __restrict__ b2,
                      const float* __restrict__ b3,
                      const unsigned short* __restrict__ w1p,
                      const unsigned short* __restrict__ w2p,
                      const unsigned short* __restrict__ w3p,
                      float* __restrict__ out) {
  __shared__ __align__(16) unsigned short lds[64 * 512];  // 64KB
  const int tid   = threadIdx.x;
  const int w     = tid >> 6;          // 4 waves
  const int lane  = tid & 63;
  const int ln31  = lane & 31;
  const int khalf = lane >> 5;
  const int m0    = blockIdx.x * 64;

  // ---- stage x tile: 64 rows x 32 chunks (fp32 -> bf16) ----
  #pragma unroll
  for (int c = tid; c < 2048; c += 256) {
    int row = c >> 5, ch = c & 31;
    const float4* src = (const float4*)(x + (size_t)(m0 + row) * 256 + ch * 8);
    float4 f0 = src[0], f1 = src[1];
    u16x8 v;
    v[0] = f2bf(f0.x); v[1] = f2bf(f0.y); v[2] = f2bf(f0.z); v[3] = f2bf(f0.w);
    v[4] = f2bf(f1.x); v[5] = f2bf(f1.y); v[6] = f2bf(f1.z); v[7] = f2bf(f1.w);
    *(u16x8*)&lds[LDSIDX(ch, row)] = v;
  }
  __syncthreads();

  const int ncb = w * 128;             // this wave's 128 hidden cols

  f32x16 acc[2][4];
  #pragma unroll
  for (int mt = 0; mt < 2; ++mt)
    #pragma unroll
    for (int nt = 0; nt < 4; ++nt)
      #pragma unroll
      for (int r = 0; r < 16; ++r) acc[mt][nt][r] = 0.f;

  // ---- Layer 1: K=256 (16 kk), wave tile 64x128 ----
  {
    const s16x8* bp = (const s16x8*)w1p + lane;   // + (tile*16 + kk)*64
    s16x8 a0 = *(const s16x8*)&lds[LDSIDX(khalf, ln31)];
    s16x8 a1 = *(const s16x8*)&lds[LDSIDX(khalf, 32 + ln31)];
    s16x8 b[4];
    #pragma unroll
    for (int nt = 0; nt < 4; ++nt) b[nt] = bp[(size_t)((w * 4 + nt) * 16) * 64];
    #pragma unroll 2
    for (int kk = 0; kk < 16; ++kk) {
      s16x8 na0, na1, nb[4];
      int nk = (kk + 1 < 16) ? kk + 1 : 15;
      int nch = nk * 2 + khalf;
      na0 = *(const s16x8*)&lds[LDSIDX(nch, ln31)];
      na1 = *(const s16x8*)&lds[LDSIDX(nch, 32 + ln31)];
      #pragma unroll
      for (int nt = 0; nt < 4; ++nt) nb[nt] = bp[(size_t)((w * 4 + nt) * 16 + nk) * 64];
      #pragma unroll
      for (int nt = 0; nt < 4; ++nt) {
        acc[0][nt] = __builtin_amdgcn_mfma_f32_32x32x16_bf16(a0, b[nt], acc[0][nt], 0, 0, 0);
        acc[1][nt] = __builtin_amdgcn_mfma_f32_32x32x16_bf16(a1, b[nt], acc[1][nt], 0, 0, 0);
      }
      a0 = na0; a1 = na1;
      #pragma unroll
      for (int nt = 0; nt < 4; ++nt) b[nt] = nb[nt];
    }
  }
  __syncthreads();

  {
    #pragma unroll
    for (int nt = 0; nt < 4; ++nt) {
      int hc = ncb + nt * 32 + ln31;
      float bias = b1[hc];
      int chh = hc >> 3, wi = hc & 7;
      #pragma unroll
      for (int mt = 0; mt < 2; ++mt)
        #pragma unroll
        for (int r = 0; r < 16; ++r) {
          int m = mt * 32 + (r & 3) + 8 * (r >> 2) + 4 * khalf;
          lds[(chh << 9) + (((m + chh) & 63) << 3) + wi] =
              f2bf(tanh_fast(acc[mt][nt][r] + bias));
        }
    }
  }
  __syncthreads();

  // ---- Layer 2: K=512 (32 kk), wave tile 64x128 ----
  #pragma unroll
  for (int mt = 0; mt < 2; ++mt)
    #pragma unroll
    for (int nt = 0; nt < 4; ++nt)
      #pragma unroll
      for (int r = 0; r < 16; ++r) acc[mt][nt][r] = 0.f;

  {
    const s16x8* bp = (const s16x8*)w2p + lane;
    s16x8 a0 = *(const s16x8*)&lds[LDSIDX(khalf, ln31)];
    s16x8 a1 = *(const s16x8*)&lds[LDSIDX(khalf, 32 + ln31)];
    s16x8 b[4];
    #pragma unroll
    for (int nt = 0; nt < 4; ++nt) b[nt] = bp[(size_t)((w * 4 + nt) * 32) * 64];
    #pragma unroll 2
    for (int kk = 0; kk < 32; ++kk) {
      s16x8 na0, na1, nb[4];
      int nk = (kk + 1 < 32) ? kk + 1 : 31;
      int nch = nk * 2 + khalf;
      na0 = *(const s16x8*)&lds[LDSIDX(nch, ln31)];
      na1 = *(const s16x8*)&lds[LDSIDX(nch, 32 + ln31)];
      #pragma unroll
      for (int nt = 0; nt < 4; ++nt) nb[nt] = bp[(size_t)((w * 4 + nt) * 32 + nk) * 64];
      #pragma unroll
      for (int nt = 0; nt < 4; ++nt) {
        acc[0][nt] = __builtin_amdgcn_mfma_f32_32x32x16_bf16(a0, b[nt], acc[0][nt], 0, 0, 0);
        acc[1][nt] = __builtin_amdgcn_mfma_f32_32x32x16_bf16(a1, b[nt], acc[1][nt], 0, 0, 0);
      }
      a0 = na0; a1 = na1;
      #pragma unroll
      for (int nt = 0; nt < 4; ++nt) b[nt] = nb[nt];
    }
  }
  __syncthreads();

  {
    #pragma unroll
    for (int nt = 0; nt < 4; ++nt) {
      int hc = ncb + nt * 32 + ln31;
      float bias = b2[hc];
      int chh = hc >> 3, wi = hc & 7;
      #pragma unroll
      for (int mt = 0; mt < 2; ++mt)
        #pragma unroll
        for (int r = 0; r < 16; ++r) {
          int m = mt * 32 + (r & 3) + 8 * (r >> 2) + 4 * khalf;
          lds[(chh << 9) + (((m + chh) & 63) << 3) + wi] =
              f2bf(tanh_fast(acc[mt][nt][r] + bias));
        }
    }
  }
  __syncthreads();

  // ---- Layer 3: out 64x128; wave w -> cols w*32..w*32+31, rows 0..63, K=512 ----
  {
    f32x16 acc3[2];
    #pragma unroll
    for (int mt = 0; mt < 2; ++mt)
      #pragma unroll
      for (int r = 0; r < 16; ++r) acc3[mt][r] = 0.f;
    const s16x8* bp = (const s16x8*)w3p + lane;
    s16x8 a0 = *(const s16x8*)&lds[LDSIDX(khalf, ln31)];
    s16x8 a1 = *(const s16x8*)&lds[LDSIDX(khalf, 32 + ln31)];
    s16x8 b = bp[(size_t)(w * 32) * 64];
    #pragma unroll 2
    for (int kk = 0; kk < 32; ++kk) {
      s16x8 na0, na1, nb;
      int nk = (kk + 1 < 32) ? kk + 1 : 31;
      int nch = nk * 2 + khalf;
      na0 = *(const s16x8*)&lds[LDSIDX(nch, ln31)];
      na1 = *(const s16x8*)&lds[LDSIDX(nch, 32 + ln31)];
      nb  = bp[(size_t)(w * 32 + nk) * 64];
      acc3[0] = __builtin_amdgcn_mfma_f32_32x32x16_bf16(a0, b, acc3[0], 0, 0, 0);
      acc3[1] = __builtin_amdgcn_mfma_f32_32x32x16_bf16(a1, b, acc3[1], 0, 0, 0);
      a0 = na0; a1 = na1; b = nb;
    }
    float bz = b3[w * 32 + ln31];
    #pragma unroll
    for (int mt = 0; mt < 2; ++mt)
      #pragma unroll
      for (int r = 0; r < 16; ++r) {
        int m = m0 + mt * 32 + (r & 3) + 8 * (r >> 2) + 4 * khalf;
        out[(size_t)m * 128 + w * 32 + ln31] = acc3[mt][r] + bz;
      }
  }
}

extern "C" void kernel_launch(void* const* d_in, const int* in_sizes, int n_in,
                              void* d_out, int out_size, void* d_ws, size_t ws_size,
                              hipStream_t stream) {
  const float* x  = (const float*)d_in[0];
  const float* W1 = (const float*)d_in[1];
  const float* b1 = (const float*)d_in[2];
  const float* W2 = (const float*)d_in[3];
  const float* b2 = (const float*)d_in[4];
  const float* W3 = (const float*)d_in[5];
  const float* b3 = (const float*)d_in[6];
  float* out = (float*)d_out;
  unsigned short* ws = (unsigned short*)d_ws;   // 458752 bf16 = 896KB

  hipLaunchKernelGGL(prep_pack, dim3(112), dim3(256), 0, stream, W1, W2, W3, ws);
  hipLaunchKernelGGL(mlp_limit_kernel, dim3(2048), dim3(256), 0, stream,
                     x, b1, b2, b3, ws, ws + 131072, ws + 393216, out);
}

// Round 5
// 328.877 us; speedup vs baseline: 1.4179x; 1.4179x over previous
//
#include <hip/hip_runtime.h>

typedef short s16x8 __attribute__((ext_vector_type(8)));
typedef unsigned short u16x8 __attribute__((ext_vector_type(8)));
typedef float f32x16 __attribute__((ext_vector_type(16)));

__device__ __forceinline__ unsigned short f2bf(float f) {
  unsigned u = __float_as_uint(f);
  u += 0x7fffu + ((u >> 16) & 1u);            // round-to-nearest-even
  return (unsigned short)(u >> 16);
}

__device__ __forceinline__ float tanh_fast(float x) {
  float xc = fminf(15.f, fmaxf(-15.f, x));
  float t = __builtin_amdgcn_exp2f(xc * 2.8853900817779268f); // 2*log2(e)
  return (t - 1.f) * __builtin_amdgcn_rcpf(t + 1.f);
}

// ---- prep: pack W (K,N) fp32 -> bf16 MFMA-B-fragment order, via LDS transpose ----
// chunk c = ((tile*KK + kk)*64 + lane), elems j=0..7:
//   value = W[(kk*16 + (lane>>5)*8 + j) * N + tile*32 + (lane&31)]
__global__ __launch_bounds__(256)
void prep_pack(const float* __restrict__ W1, const float* __restrict__ W2,
               const float* __restrict__ W3, unsigned short* __restrict__ ws) {
  __shared__ unsigned short t[64][65];
  const int b = blockIdx.x;
  const float* W; unsigned short* base; int KK, N, tk, tn;
  if (b < 32)      { W = W1; base = ws;          KK = 16; N = 512; tk = b >> 3;       tn = b & 7; }
  else if (b < 96) { int g = b - 32; W = W2; base = ws + 131072; KK = 32; N = 512; tk = g >> 3; tn = g & 7; }
  else             { int g = b - 96; W = W3; base = ws + 393216; KK = 32; N = 128; tk = g >> 1; tn = g & 1; }

  const int tid = threadIdx.x;
  #pragma unroll
  for (int p = 0; p < 16; ++p) {
    int kl = p * 4 + (tid >> 6);
    int nl = tid & 63;
    t[kl][nl] = f2bf(W[(size_t)(tk * 64 + kl) * N + tn * 64 + nl]);
  }
  __syncthreads();

  const int lane = tid & 63, ln31 = lane & 31, khalf = lane >> 5;
  #pragma unroll
  for (int pass = 0; pass < 2; ++pass) {
    int pair = pass * 4 + (tid >> 6);
    int tn_l = pair & 1, kk_l = pair >> 1;
    int tile = tn * 2 + tn_l, kk = tk * 4 + kk_l;
    u16x8 v;
    #pragma unroll
    for (int j = 0; j < 8; ++j)
      v[j] = t[kk_l * 16 + khalf * 8 + j][tn_l * 32 + ln31];
    *(u16x8*)(base + ((size_t)(tile * KK + kk) * 64 + lane) * 8) = v;
  }
}

// h LDS layout: row-major, 16B chunks XOR-swizzled by (row&7).
// short-index(row, ch, wi) = row*512 + ((ch ^ (row&7))*8) + wi
// A-frag addr for lane with fixed row: base ^ (ch*8)  -> 1 VALU per read.
#define ABASE(row) ((row) * 512 + ((row) & 7) * 8)

__global__ __launch_bounds__(512, 4)
void mlp_limit_kernel(const float* __restrict__ x,
                      const float* __restrict__ b1, const float* __restrict__ b2,
                      const float* __restrict__ b3,
                      const unsigned short* __restrict__ w1p,
                      const unsigned short* __restrict__ w2p,
                      const unsigned short* __restrict__ w3p,
                      float* __restrict__ out) {
  __shared__ __align__(16) unsigned short lds[64 * 512];  // 64KB
  const int tid   = threadIdx.x;
  const int w     = __builtin_amdgcn_readfirstlane(tid >> 6);  // wave id in SGPR
  const int lane  = tid & 63;
  const int ln31  = lane & 31;
  const int khalf = lane >> 5;
  const int m0    = blockIdx.x * 64;

  // ---- stage x tile: 64 rows x 32 chunks (fp32 -> bf16) ----
  #pragma unroll
  for (int c = tid; c < 2048; c += 512) {
    int row = c >> 5, ch = c & 31;
    const float4* src = (const float4*)(x + (size_t)(m0 + row) * 256 + ch * 8);
    float4 f0 = src[0], f1 = src[1];
    u16x8 v;
    v[0] = f2bf(f0.x); v[1] = f2bf(f0.y); v[2] = f2bf(f0.z); v[3] = f2bf(f0.w);
    v[4] = f2bf(f1.x); v[5] = f2bf(f1.y); v[6] = f2bf(f1.z); v[7] = f2bf(f1.w);
    *(u16x8*)&lds[row * 512 + ((ch ^ (row & 7)) * 8)] = v;
  }
  __syncthreads();

  const int abase0 = ABASE(ln31);
  const int abase1 = ABASE(ln31 + 32);
  const int ncb    = w * 64;           // this wave's 64 hidden cols
  const int kh32   = khalf * 32;       // epilogue addr helper
  const int khA    = khalf * 8;        // A chunk offset within kk (ch = 2kk+khalf)

  f32x16 acc[2][2];

  // ================= Layer 1: K=256 (16 kk), wave tile 64x64 =================
  #pragma unroll
  for (int mt = 0; mt < 2; ++mt)
    #pragma unroll
    for (int nt = 0; nt < 2; ++nt)
      #pragma unroll
      for (int r = 0; r < 16; ++r) acc[mt][nt][r] = 0.f;
  {
    const s16x8* bp0 = (const s16x8*)w1p + (size_t)((w * 2 + 0) * 16) * 64 + lane;
    const s16x8* bp1 = (const s16x8*)w1p + (size_t)((w * 2 + 1) * 16) * 64 + lane;
    s16x8 a0[2], a1[2], b0[2], b1[2];
    b0[0] = bp0[0];  b1[0] = bp1[0];
    b0[1] = bp0[64]; b1[1] = bp1[64];
    a0[0] = *(const s16x8*)&lds[abase0 ^ khA];
    a1[0] = *(const s16x8*)&lds[abase1 ^ khA];
    #pragma unroll
    for (int kk = 0; kk < 16; ++kk) {
      const int s = kk & 1, d = s ^ 1;
      if (kk + 1 < 16) {
        a0[d] = *(const s16x8*)&lds[abase0 ^ ((kk + 1) * 16 + khA)];
        a1[d] = *(const s16x8*)&lds[abase1 ^ ((kk + 1) * 16 + khA)];
      }
      acc[0][0] = __builtin_amdgcn_mfma_f32_32x32x16_bf16(a0[s], b0[s], acc[0][0], 0, 0, 0);
      acc[0][1] = __builtin_amdgcn_mfma_f32_32x32x16_bf16(a0[s], b1[s], acc[0][1], 0, 0, 0);
      acc[1][0] = __builtin_amdgcn_mfma_f32_32x32x16_bf16(a1[s], b0[s], acc[1][0], 0, 0, 0);
      acc[1][1] = __builtin_amdgcn_mfma_f32_32x32x16_bf16(a1[s], b1[s], acc[1][1], 0, 0, 0);
      if (kk + 2 < 16) {
        b0[s] = bp0[(kk + 2) * 64];
        b1[s] = bp1[(kk + 2) * 64];
      }
    }
  }
  __syncthreads();    // all x reads done

  #pragma unroll
  for (int nt = 0; nt < 2; ++nt) {
    int hc = ncb + nt * 32 + ln31;
    float bias = b1[hc];
    int wi = hc & 7;
    int e  = (((hc >> 3) * 8) ^ kh32) + wi + khalf * 2048;   // runtime part
    #pragma unroll
    for (int mt = 0; mt < 2; ++mt)
      #pragma unroll
      for (int r = 0; r < 16; ++r) {
        int C = (mt * 32 + (r & 3) + 8 * (r >> 2)) * 512;    // compile-time
        lds[C + (e ^ ((r & 3) * 8))] = f2bf(tanh_fast(acc[mt][nt][r] + bias));
      }
  }
  __syncthreads();

  // ================= Layer 2: K=512 (32 kk), wave tile 64x64 =================
  #pragma unroll
  for (int mt = 0; mt < 2; ++mt)
    #pragma unroll
    for (int nt = 0; nt < 2; ++nt)
      #pragma unroll
      for (int r = 0; r < 16; ++r) acc[mt][nt][r] = 0.f;
  {
    const s16x8* bp0 = (const s16x8*)w2p + (size_t)((w * 2 + 0) * 32) * 64 + lane;
    const s16x8* bp1 = (const s16x8*)w2p + (size_t)((w * 2 + 1) * 32) * 64 + lane;
    s16x8 a0[2], a1[2], b0[2], b1[2];
    b0[0] = bp0[0];  b1[0] = bp1[0];
    b0[1] = bp0[64]; b1[1] = bp1[64];
    a0[0] = *(const s16x8*)&lds[abase0 ^ khA];
    a1[0] = *(const s16x8*)&lds[abase1 ^ khA];
    #pragma unroll
    for (int kk = 0; kk < 32; ++kk) {
      const int s = kk & 1, d = s ^ 1;
      if (kk + 1 < 32) {
        a0[d] = *(const s16x8*)&lds[abase0 ^ ((kk + 1) * 16 + khA)];
        a1[d] = *(const s16x8*)&lds[abase1 ^ ((kk + 1) * 16 + khA)];
      }
      acc[0][0] = __builtin_amdgcn_mfma_f32_32x32x16_bf16(a0[s], b0[s], acc[0][0], 0, 0, 0);
      acc[0][1] = __builtin_amdgcn_mfma_f32_32x32x16_bf16(a0[s], b1[s], acc[0][1], 0, 0, 0);
      acc[1][0] = __builtin_amdgcn_mfma_f32_32x32x16_bf16(a1[s], b0[s], acc[1][0], 0, 0, 0);
      acc[1][1] = __builtin_amdgcn_mfma_f32_32x32x16_bf16(a1[s], b1[s], acc[1][1], 0, 0, 0);
      if (kk + 2 < 32) {
        b0[s] = bp0[(kk + 2) * 64];
        b1[s] = bp1[(kk + 2) * 64];
      }
    }
  }
  __syncthreads();    // all h1 reads done

  #pragma unroll
  for (int nt = 0; nt < 2; ++nt) {
    int hc = ncb + nt * 32 + ln31;
    float bias = b2[hc];
    int wi = hc & 7;
    int e  = (((hc >> 3) * 8) ^ kh32) + wi + khalf * 2048;
    #pragma unroll
    for (int mt = 0; mt < 2; ++mt)
      #pragma unroll
      for (int r = 0; r < 16; ++r) {
        int C = (mt * 32 + (r & 3) + 8 * (r >> 2)) * 512;
        lds[C + (e ^ ((r & 3) * 8))] = f2bf(tanh_fast(acc[mt][nt][r] + bias));
      }
  }
  __syncthreads();

  // ===== Layer 3: out 64x128; 8 waves as 2m x 4n of 32x32 tiles, K=512 =====
  {
    const int mh  = (w >> 2) * 32;            // row half
    const int t3  = w & 3;                    // col tile
    const int ab  = ABASE(mh + ln31);
    f32x16 acc3;
    #pragma unroll
    for (int r = 0; r < 16; ++r) acc3[r] = 0.f;
    const s16x8* bp = (const s16x8*)w3p + (size_t)(t3 * 32) * 64 + lane;
    s16x8 a[2], b[2];
    b[0] = bp[0]; b[1] = bp[64];
    a[0] = *(const s16x8*)&lds[ab ^ khA];
    #pragma unroll
    for (int kk = 0; kk < 32; ++kk) {
      const int s = kk & 1, d = s ^ 1;
      if (kk + 1 < 32)
        a[d] = *(const s16x8*)&lds[ab ^ ((kk + 1) * 16 + khA)];
      acc3 = __builtin_amdgcn_mfma_f32_32x32x16_bf16(a[s], b[s], acc3, 0, 0, 0);
      if (kk + 2 < 32) b[s] = bp[(kk + 2) * 64];
    }
    float bz = b3[t3 * 32 + ln31];
    #pragma unroll
    for (int r = 0; r < 16; ++r) {
      int m = m0 + mh + (r & 3) + 8 * (r >> 2) + 4 * khalf;
      out[(size_t)m * 128 + t3 * 32 + ln31] = acc3[r] + bz;
    }
  }
}

extern "C" void kernel_launch(void* const* d_in, const int* in_sizes, int n_in,
                              void* d_out, int out_size, void* d_ws, size_t ws_size,
                              hipStream_t stream) {
  const float* x  = (const float*)d_in[0];
  const float* W1 = (const float*)d_in[1];
  const float* b1 = (const float*)d_in[2];
  const float* W2 = (const float*)d_in[3];
  const float* b2 = (const float*)d_in[4];
  const float* W3 = (const float*)d_in[5];
  const float* b3 = (const float*)d_in[6];
  float* out = (float*)d_out;
  unsigned short* ws = (unsigned short*)d_ws;   // 458752 bf16 = 896KB

  hipLaunchKernelGGL(prep_pack, dim3(112), dim3(256), 0, stream, W1, W2, W3, ws);
  hipLaunchKernelGGL(mlp_limit_kernel, dim3(2048), dim3(512), 0, stream,
                     x, b1, b2, b3, ws, ws + 131072, ws + 393216, out);
}